// Round 2
// baseline (169.004 us; speedup 1.0000x reference)
//
#include <hip/hip_runtime.h>
#include <hip/hip_bf16.h>

// VectorQuantizer: x [32768 x 64] fp32, embeddings e [64 x 1024] fp32.
// d_out = [out (2097152 f32) = x + (q - x), loss (1 f32) = 1.25*mean((q-x)^2)].
//
// Strategy: bf16x3-split MFMA (xh*eh + xh*el + xl*eh) computes approx distance
// keys se[k] - 2*dot (per-row constant sx dropped; argmin invariant). Rows whose
// (best2 - best) gap < MARGIN are exactly re-scored in fp32 with the identical
// formula/summation order that passed round 1 (absmax 0.0 vs numpy).

#define NROWS 32768
#define DDIM  64
#define KCODE 1024
#define NELEM (NROWS * DDIM)
#define ROWS_PB 32
#define MARGIN 5e-4f

typedef __attribute__((ext_vector_type(8))) short bf16x8;  // 8 bf16 in 4 VGPRs
typedef __attribute__((ext_vector_type(4))) float f32x4;

static __device__ __forceinline__ unsigned short f2bf(float v) {
    __hip_bfloat16 h = __float2bfloat16(v);
    unsigned short b;
    __builtin_memcpy(&b, &h, 2);
    return b;
}
static __device__ __forceinline__ float bf2f(unsigned short b) {
    unsigned int u = ((unsigned int)b) << 16;
    float f;
    __builtin_memcpy(&f, &u, 4);
    return f;
}

// ---------------------------------------------------------------------------
// prep: se[k] (exact fp32, ascending-d fmaf — must match recheck), eT[k][d]
// fp32, ehT/elT[k][d] bf16 splits. 16 blocks x 256 thr, coalesced LDS transpose.
__global__ void vq_prep(const float* __restrict__ e,
                        float* __restrict__ se,
                        float* __restrict__ eT,
                        unsigned short* __restrict__ ehT,
                        unsigned short* __restrict__ elT) {
    __shared__ float tile[64][65];
    const int t = threadIdx.x;
    const int k0 = blockIdx.x * 64;
    #pragma unroll
    for (int i = 0; i < 16; ++i) {
        int idx = i * 256 + t;
        int d = idx >> 6, kk = idx & 63;
        tile[d][kk] = e[d * KCODE + k0 + kk];
    }
    __syncthreads();
    if (t < 64) {
        float s = 0.f;
        #pragma unroll
        for (int d = 0; d < 64; ++d) { float v = tile[d][t]; s = fmaf(v, v, s); }
        se[k0 + t] = s;
    }
    const int kk = t >> 2, dg = (t & 3) * 16;
    const int kg = k0 + kk;
    #pragma unroll
    for (int d = dg; d < dg + 16; ++d) {
        float v = tile[d][kk];
        eT[(size_t)kg * 64 + d] = v;
        unsigned short hb = f2bf(v);
        float hf = bf2f(hb);
        unsigned short lb = f2bf(v - hf);
        ehT[(size_t)kg * 64 + d] = hb;
        elT[(size_t)kg * 64 + d] = lb;
    }
}

// ---------------------------------------------------------------------------
__launch_bounds__(256)
__global__ void vq_main(const float* __restrict__ x,
                        const float* __restrict__ se,
                        const float* __restrict__ eT,
                        const unsigned short* __restrict__ ehT,
                        const unsigned short* __restrict__ elT,
                        float* __restrict__ out,
                        float* __restrict__ lossAcc) {
    __shared__ float xs[ROWS_PB][64];          // fp32 x rows
    __shared__ unsigned short shh[ROWS_PB][64];  // bf16 hi
    __shared__ unsigned short shl[ROWS_PB][64];  // bf16 lo
    __shared__ float ssa[KCODE];               // se staged
    __shared__ float sxr[ROWS_PB];             // sum x^2 (exact, for recheck)
    __shared__ float rb [ROWS_PB][65];
    __shared__ float rb2[ROWS_PB][65];
    __shared__ int   ri [ROWS_PB][65];
    __shared__ int   rowIdx[ROWS_PB];
    __shared__ int   rowFlag[ROWS_PB];
    __shared__ float candb[256];
    __shared__ int   candi[256];
    __shared__ float wloss[4];

    const int t = threadIdx.x;
    const int row0 = blockIdx.x * ROWS_PB;

    // ---- stage x (coalesced), build bf16 splits, stage se ----
    {
        const float4* xp = (const float4*)(x + (size_t)row0 * 64);
        float4 v0 = xp[t * 2], v1 = xp[t * 2 + 1];
        int r = t >> 3, c = (t & 7) * 8;
        float vv[8] = {v0.x, v0.y, v0.z, v0.w, v1.x, v1.y, v1.z, v1.w};
        #pragma unroll
        for (int i = 0; i < 8; ++i) {
            float v = vv[i];
            xs[r][c + i] = v;
            unsigned short hb = f2bf(v);
            shh[r][c + i] = hb;
            shl[r][c + i] = f2bf(v - bf2f(hb));
        }
        float4 s4 = ((const float4*)se)[t];
        ssa[t * 4 + 0] = s4.x; ssa[t * 4 + 1] = s4.y;
        ssa[t * 4 + 2] = s4.z; ssa[t * 4 + 3] = s4.w;
    }
    __syncthreads();

    if (t < ROWS_PB) {  // exact sx, same order as reference recheck path
        float s = 0.f;
        #pragma unroll
        for (int d = 0; d < 64; ++d) s = fmaf(xs[t][d], xs[t][d], s);
        sxr[t] = s;
    }

    // ---- MFMA scan: 4 waves x 256-code chunks ----
    const int lane = t & 63;
    const int w = __builtin_amdgcn_readfirstlane(t >> 6);
    const int quad = lane >> 4, l15 = lane & 15;

    bf16x8 ah[2][2], al[2][2];
    #pragma unroll
    for (int mt = 0; mt < 2; ++mt)
        #pragma unroll
        for (int ks = 0; ks < 2; ++ks) {
            ah[mt][ks] = *(const bf16x8*)&shh[mt * 16 + l15][quad * 8 + ks * 32];
            al[mt][ks] = *(const bf16x8*)&shl[mt * 16 + l15][quad * 8 + ks * 32];
        }

    float sb[2][4], sb2[2][4];
    int   si[2][4];
    #pragma unroll
    for (int mt = 0; mt < 2; ++mt)
        #pragma unroll
        for (int r = 0; r < 4; ++r) { sb[mt][r] = 3.4e38f; sb2[mt][r] = 3.4e38f; si[mt][r] = 0; }

    const int cb = w * 256;
    for (int nt = 0; nt < 16; ++nt) {
        const int nl = cb + nt * 16 + l15;
        const bf16x8* bhp = (const bf16x8*)(ehT + (size_t)nl * 64 + quad * 8);
        const bf16x8* blp = (const bf16x8*)(elT + (size_t)nl * 64 + quad * 8);
        bf16x8 bh0 = bhp[0], bh1 = bhp[4];   // +32 bf16 elems
        bf16x8 bl0 = blp[0], bl1 = blp[4];
        float sen = ssa[nl];
        #pragma unroll
        for (int mt = 0; mt < 2; ++mt) {
            f32x4 acc = {0.f, 0.f, 0.f, 0.f};
            acc = __builtin_amdgcn_mfma_f32_16x16x32_bf16(ah[mt][0], bh0, acc, 0, 0, 0);
            acc = __builtin_amdgcn_mfma_f32_16x16x32_bf16(ah[mt][1], bh1, acc, 0, 0, 0);
            acc = __builtin_amdgcn_mfma_f32_16x16x32_bf16(ah[mt][0], bl0, acc, 0, 0, 0);
            acc = __builtin_amdgcn_mfma_f32_16x16x32_bf16(ah[mt][1], bl1, acc, 0, 0, 0);
            acc = __builtin_amdgcn_mfma_f32_16x16x32_bf16(al[mt][0], bh0, acc, 0, 0, 0);
            acc = __builtin_amdgcn_mfma_f32_16x16x32_bf16(al[mt][1], bh1, acc, 0, 0, 0);
            #pragma unroll
            for (int r = 0; r < 4; ++r) {
                float d = fmaf(-2.f, acc[r], sen);   // key = se - 2*dot
                float bo = sb[mt][r];
                sb[mt][r] = fminf(bo, d);
                si[mt][r] = (d < bo) ? nl : si[mt][r];
                sb2[mt][r] = fminf(sb2[mt][r], fmaxf(bo, d));
            }
        }
    }

    // ---- cross-lane/wave argmin reduce ----
    const int col = w * 16 + l15;
    #pragma unroll
    for (int mt = 0; mt < 2; ++mt)
        #pragma unroll
        for (int r = 0; r < 4; ++r) {
            int rr = mt * 16 + quad * 4 + r;
            rb [rr][col] = sb [mt][r];
            rb2[rr][col] = sb2[mt][r];
            ri [rr][col] = si [mt][r];
        }
    __syncthreads();

    if (t < ROWS_PB) {
        float B = rb[t][0], B2 = rb2[t][0];
        int I = ri[t][0];
        for (int c = 1; c < 64; ++c) {
            float b = rb[t][c], b2 = rb2[t][c];
            int i = ri[t][c];
            float nB2 = fminf(fminf(B2, b2), fmaxf(B, b));
            if (b < B || (b == B && i < I)) { B = b; I = i; }
            B2 = nB2;
        }
        rowIdx[t]  = I;
        rowFlag[t] = (B2 - B < MARGIN) ? 1 : 0;
    }
    __syncthreads();

    // ---- exact fp32 recheck for flagged rows (rare; replicates round-1 math) ----
    for (int r = 0; r < ROWS_PB; ++r) {
        if (rowFlag[r]) {
            float sx = sxr[r];
            float db = 3.4e38f; int di = 0;
            #pragma unroll
            for (int j = 0; j < 4; ++j) {
                int k = t * 4 + j;                    // thread t owns codes 4t..4t+3
                const float* ep = eT + (size_t)k * 64;
                float dot = 0.f;
                for (int d = 0; d < 64; ++d) dot = fmaf(xs[r][d], ep[d], dot);
                float t0 = sx + ssa[k];
                float dd = t0 - 2.0f * dot;
                if (dd < db) { db = dd; di = k; }
            }
            candb[t] = db; candi[t] = di;
            __syncthreads();
            if (t == 0) {
                float B = candb[0]; int I = candi[0];
                for (int c = 1; c < 256; ++c)
                    if (candb[c] < B) { B = candb[c]; I = candi[c]; }
                rowIdx[r] = I;
            }
            __syncthreads();
        }
    }
    __syncthreads();

    // ---- epilogue: gather q, straight-through out, loss partial ----
    {
        int r = t >> 3, c = (t & 7) * 8;
        int idx = rowIdx[r];
        const float4* qp = (const float4*)(eT + (size_t)idx * 64 + c);
        float4 q0 = qp[0], q1 = qp[1];
        float qv[8] = {q0.x, q0.y, q0.z, q0.w, q1.x, q1.y, q1.z, q1.w};
        float ov[8];
        float lsum = 0.f;
        #pragma unroll
        for (int i = 0; i < 8; ++i) {
            float xv = xs[r][c + i];
            float dx = qv[i] - xv;
            ov[i] = xv + dx;
            lsum = fmaf(dx, dx, lsum);
        }
        float4* op = (float4*)(out + (size_t)(row0 + r) * 64 + c);
        op[0] = make_float4(ov[0], ov[1], ov[2], ov[3]);
        op[1] = make_float4(ov[4], ov[5], ov[6], ov[7]);

        #pragma unroll
        for (int off = 32; off > 0; off >>= 1)
            lsum += __shfl_down(lsum, off, 64);
        if (lane == 0) wloss[w] = lsum;
    }
    __syncthreads();
    if (t == 0) {
        float s = wloss[0] + wloss[1] + wloss[2] + wloss[3];
        atomicAdd(lossAcc, s);
    }
}

__global__ void vq_loss(const float* __restrict__ lossAcc,
                        float* __restrict__ out) {
    float m = lossAcc[0] / (float)NELEM;
    out[NELEM] = 0.25f * m + m;
}

extern "C" void kernel_launch(void* const* d_in, const int* in_sizes, int n_in,
                              void* d_out, int out_size, void* d_ws, size_t ws_size,
                              hipStream_t stream) {
    const float* x = (const float*)d_in[0];
    const float* e = (const float*)d_in[1];
    float* out = (float*)d_out;
    float* ws  = (float*)d_ws;

    float* lossAcc      = ws;
    float* se           = ws + 64;
    float* eT           = ws + 2048;                        // 65536 f
    unsigned short* ehT = (unsigned short*)(ws + 67584);    // 65536 bf16
    unsigned short* elT = (unsigned short*)(ws + 100352);   // 65536 bf16

    hipMemsetAsync(d_ws, 0, sizeof(float), stream);
    vq_prep<<<16, 256, 0, stream>>>(e, se, eT, ehT, elT);
    vq_main<<<NROWS / ROWS_PB, 256, 0, stream>>>(x, se, eT, ehT, elT, out, lossAcc);
    vq_loss<<<1, 1, 0, stream>>>(lossAcc, out);
}